// Round 2
// baseline (13545.572 us; speedup 1.0000x reference)
//
#include <hip/hip_runtime.h>
#include <math.h>

// Problem constants
#define B_    128
#define P_    197
#define D_    768
#define TOK_  512
#define K_    16
#define TOPK_ 8
#define L_    2
#define H_    12
#define HD_   64
#define NTOK  213            // K_ + P_
#define MROWS (B_ * NTOK)    // 27264

__device__ __forceinline__ float wred_sum(float v) {
#pragma unroll
  for (int o = 32; o > 0; o >>= 1) v += __shfl_xor(v, o);
  return v;
}
__device__ __forceinline__ float wred_max(float v) {
#pragma unroll
  for (int o = 32; o > 0; o >>= 1) v = fmaxf(v, __shfl_xor(v, o));
  return v;
}

// ---------------- concat: x = [templates broadcast | img_patch_feats] ----
__global__ __launch_bounds__(256) void concat_kernel(
    const float* __restrict__ tpl, const float* __restrict__ patches,
    float* __restrict__ x) {
  size_t i = (size_t)blockIdx.x * 256 + threadIdx.x;  // one float4 each
  const size_t total = (size_t)MROWS * (D_ / 4);
  if (i >= total) return;
  size_t row = i / (D_ / 4);
  int c = (int)(i % (D_ / 4)) * 4;
  size_t b = row / NTOK;
  int n = (int)(row % NTOK);
  float4 v;
  if (n < K_) v = *(const float4*)(tpl + (size_t)n * D_ + c);
  else        v = *(const float4*)(patches + ((size_t)b * P_ + (n - K_)) * D_ + c);
  *(float4*)(x + row * D_ + c) = v;
}

// ---------------- LayerNorm: one wave per row ----------------------------
__global__ __launch_bounds__(64) void ln_kernel(
    const float* __restrict__ x, const float* __restrict__ w,
    const float* __restrict__ b, float* __restrict__ y) {
  size_t row = blockIdx.x;
  int lane = threadIdx.x;
  const float* xr = x + row * D_;
  float4 v[3];
#pragma unroll
  for (int j = 0; j < 3; ++j) v[j] = *(const float4*)(xr + j * 256 + lane * 4);
  float s = 0.f, sq = 0.f;
#pragma unroll
  for (int j = 0; j < 3; ++j) {
    s += v[j].x + v[j].y + v[j].z + v[j].w;
    sq = fmaf(v[j].x, v[j].x, sq); sq = fmaf(v[j].y, v[j].y, sq);
    sq = fmaf(v[j].z, v[j].z, sq); sq = fmaf(v[j].w, v[j].w, sq);
  }
#pragma unroll
  for (int o = 32; o > 0; o >>= 1) { s += __shfl_xor(s, o); sq += __shfl_xor(sq, o); }
  float mean = s * (1.f / D_);
  float var = sq * (1.f / D_) - mean * mean;
  float rs = rsqrtf(var + 1e-5f);
  float* yr = y + row * D_;
#pragma unroll
  for (int j = 0; j < 3; ++j) {
    int col = j * 256 + lane * 4;
    float4 wv = *(const float4*)(w + col);
    float4 bv = *(const float4*)(b + col);
    float4 o;
    o.x = (v[j].x - mean) * rs * wv.x + bv.x;
    o.y = (v[j].y - mean) * rs * wv.y + bv.y;
    o.z = (v[j].z - mean) * rs * wv.z + bv.z;
    o.w = (v[j].w - mean) * rs * wv.w + bv.w;
    *(float4*)(yr + col) = o;
  }
}

// ---------------- fp32 GEMM: C = act(A @ W + bias) [+ C] -----------------
// BM=BN=128, BK=16, 256 threads, 8x8 per thread. Row-guarded (M arbitrary;
// N, K must be multiples of 128/16 — true for all our calls).
// ACT: 0 none, 1 relu, 2 sigmoid.  RESID: C += result.  GATHER: A row
// mapping r -> (r/16)*NTOK + (r%16)  (x[:, :K, :] row gather).
template <int ACT, bool RESID, bool GATHER>
__global__ __launch_bounds__(256) void gemm_f32(
    const float* __restrict__ A, const float* __restrict__ W,
    const float* __restrict__ bias, float* __restrict__ C,
    int M, int N, int K) {
  __shared__ float As[16][132];
  __shared__ float Ws[16][132];
  const int bm = blockIdx.x * 128;
  const int bn = blockIdx.y * 128;
  const int tid = threadIdx.x;
  const int tx = tid & 15, ty = tid >> 4;
  float acc[8][8] = {};
  for (int k0 = 0; k0 < K; k0 += 16) {
#pragma unroll
    for (int i = 0; i < 2; ++i) {        // A tile 128x16
      int r = (tid >> 2) + i * 64;
      int c = (tid & 3) * 4;
      int row = bm + r;
      if (row >= M) row = M - 1;         // clamp (stores are guarded)
      size_t arow = GATHER ? ((size_t)(row >> 4) * NTOK + (row & 15)) : (size_t)row;
      float4 v = *(const float4*)(A + arow * K + k0 + c);
      As[c + 0][r] = v.x; As[c + 1][r] = v.y;
      As[c + 2][r] = v.z; As[c + 3][r] = v.w;
    }
#pragma unroll
    for (int i = 0; i < 2; ++i) {        // W tile 16x128
      int r = (tid >> 5) + i * 8;
      int c = (tid & 31) * 4;
      float4 v = *(const float4*)(W + (size_t)(k0 + r) * N + bn + c);
      *(float4*)(&Ws[r][c]) = v;
    }
    __syncthreads();
#pragma unroll
    for (int kk = 0; kk < 16; ++kk) {
      float a[8], w8[8];
      *(float4*)&a[0]  = *(const float4*)&As[kk][ty * 8];
      *(float4*)&a[4]  = *(const float4*)&As[kk][ty * 8 + 4];
      *(float4*)&w8[0] = *(const float4*)&Ws[kk][tx * 8];
      *(float4*)&w8[4] = *(const float4*)&Ws[kk][tx * 8 + 4];
#pragma unroll
      for (int i = 0; i < 8; ++i)
#pragma unroll
        for (int j = 0; j < 8; ++j) acc[i][j] = fmaf(a[i], w8[j], acc[i][j]);
    }
    __syncthreads();
  }
  float bv[8];
#pragma unroll
  for (int j = 0; j < 8; j += 4) *(float4*)&bv[j] = *(const float4*)(bias + bn + tx * 8 + j);
#pragma unroll
  for (int i = 0; i < 8; ++i) {
    int crow = bm + ty * 8 + i;
    if (crow >= M) continue;
    float* cp = C + (size_t)crow * N + bn + tx * 8;
#pragma unroll
    for (int j = 0; j < 8; j += 4) {
      float4 r;
      r.x = acc[i][j + 0] + bv[j + 0];
      r.y = acc[i][j + 1] + bv[j + 1];
      r.z = acc[i][j + 2] + bv[j + 2];
      r.w = acc[i][j + 3] + bv[j + 3];
      if (ACT == 1) {
        r.x = fmaxf(r.x, 0.f); r.y = fmaxf(r.y, 0.f);
        r.z = fmaxf(r.z, 0.f); r.w = fmaxf(r.w, 0.f);
      } else if (ACT == 2) {
        r.x = 1.f / (1.f + expf(-r.x)); r.y = 1.f / (1.f + expf(-r.y));
        r.z = 1.f / (1.f + expf(-r.z)); r.w = 1.f / (1.f + expf(-r.w));
      }
      if (RESID) {
        float4 o = *(const float4*)(cp + j);
        r.x += o.x; r.y += o.y; r.z += o.z; r.w += o.w;
      }
      *(float4*)(cp + j) = r;
    }
  }
}

// ---------------- fused attention per (b_local, h) ------------------------
// K staged in LDS (stride 65 -> conflict-free), V streamed from global
// (lane-contiguous, L1/L2-resident). One wave per query row, full-row
// softmax. LDS total = 60.5 KB (< 64 KB).
__global__ __launch_bounds__(256) void attn_kernel(
    const float* __restrict__ q, const float* __restrict__ kv,
    float* __restrict__ o) {
  __shared__ float Ks[NTOK][65];
  __shared__ float q_s[4][64];
  __shared__ float p_s[4][256];
  const int b = blockIdx.x, h = blockIdx.y;
  const int tid = threadIdx.x;
  const int lane = tid & 63, w = tid >> 6;
  for (int idx = tid; idx < NTOK * 64; idx += 256) {
    int m = idx >> 6, d = idx & 63;
    Ks[m][d] = kv[((size_t)(b * NTOK + m) * 2) * D_ + h * HD_ + d];
  }
  __syncthreads();
  const float* vbase = kv + ((size_t)(b * NTOK) * 2 + 1) * D_ + h * HD_ + lane;
  for (int n = w; n < NTOK; n += 4) {
    q_s[w][lane] = q[((size_t)(b * NTOK + n)) * D_ + h * HD_ + lane];
    float s[4];
    float mx = -INFINITY;
#pragma unroll
    for (int c = 0; c < 4; ++c) {
      int m = lane + c * 64;
      float acc = -INFINITY;
      if (m < NTOK) {
        acc = 0.f;
#pragma unroll
        for (int d = 0; d < 64; ++d) acc = fmaf(q_s[w][d], Ks[m][d], acc);
        acc *= 0.125f;   // hd^-0.5
        mx = fmaxf(mx, acc);
      }
      s[c] = acc;
    }
    mx = wred_max(mx);
    float sum = 0.f;
#pragma unroll
    for (int c = 0; c < 4; ++c) {
      int m = lane + c * 64;
      float e = (m < NTOK) ? expf(s[c] - mx) : 0.f;
      s[c] = e;
      sum += e;
    }
    sum = wred_sum(sum);
    float inv = 1.f / sum;
#pragma unroll
    for (int c = 0; c < 4; ++c) p_s[w][lane + c * 64] = s[c] * inv;
    float acc = 0.f;
#pragma unroll 8
    for (int m = 0; m < NTOK; ++m)
      acc = fmaf(p_s[w][m], vbase[(size_t)m * 2 * D_], acc);
    o[((size_t)(b * NTOK + n)) * D_ + h * HD_ + lane] = acc;
  }
}

// ---------------- logits[b,k] = dot(lat[b,k,:], proj[b,:]) ----------------
__global__ __launch_bounds__(64) void logits_kernel(
    const float* __restrict__ lat, const float* __restrict__ proj,
    float* __restrict__ logits) {
  int bk = blockIdx.x;
  int b = bk >> 4;
  int lane = threadIdx.x;
  const float* lr = lat + (size_t)bk * TOK_;
  const float* pr = proj + (size_t)b * TOK_;
  float s = 0.f;
#pragma unroll
  for (int i = 0; i < 8; ++i) s = fmaf(lr[lane + 64 * i], pr[lane + 64 * i], s);
  s = wred_sum(s);
  if (lane == 0) logits[bk] = s;
}

// ---------------- softmax + topk select + normalize (1 wave per b) --------
__global__ __launch_bounds__(64) void select_kernel(
    const float* __restrict__ logits, const float* __restrict__ lat,
    float* __restrict__ out_sel, float* __restrict__ out_numr) {
  const int b = blockIdx.x;
  const int lane = threadIdx.x;
  __shared__ float aw_s[16];
  __shared__ int sel_id_s[8];
  __shared__ int numr_s;
  float v = (lane < 16) ? logits[b * 16 + lane] : -INFINITY;
  float mx = wred_max(v);
  float e = (lane < 16) ? expf(v - mx) : 0.f;
  float sum = wred_sum(e);
  float aw = e / sum;
  if (lane < 16) aw_s[lane] = aw;
  unsigned long long ball = __ballot(lane < 16 && aw > 0.05f);
  int counts = __popcll(ball);
  __syncthreads();
  if (lane == 0) {
    int num_r = counts < 1 ? 1 : (counts > TOPK_ ? TOPK_ : counts);
    numr_s = num_r;
    bool used[16];
#pragma unroll
    for (int i = 0; i < 16; ++i) used[i] = false;
    int sorted_idx[8];
    for (int j = 0; j < 8; ++j) {   // descending top-8 (ties: lowest index)
      float bv = -INFINITY; int bi = 0;
      for (int i = 0; i < 16; ++i)
        if (!used[i] && aw_s[i] > bv) { bv = aw_s[i]; bi = i; }
      used[bi] = true;
      sorted_idx[j] = bi;
    }
    int keys[8];
    for (int j = 0; j < 8; ++j) keys[j] = (j < num_r) ? sorted_idx[j] : (16 + j);
    bool kused[8];
    for (int j = 0; j < 8; ++j) kused[j] = false;
    for (int slot = 0; slot < 8; ++slot) {  // perm = argsort(keys), gather
      int bk = 1 << 30, bj = 0;
      for (int j = 0; j < 8; ++j)
        if (!kused[j] && keys[j] < bk) { bk = keys[j]; bj = j; }
      kused[bj] = true;
      sel_id_s[slot] = sorted_idx[bj];
    }
  }
  __syncthreads();
  for (int j = 0; j < 8; ++j) {
    int id = sel_id_s[j];
    const float* row = lat + ((size_t)b * 16 + id) * TOK_;
    float vals[8];
    float sq = 0.f;
#pragma unroll
    for (int i = 0; i < 8; ++i) {
      vals[i] = row[lane + 64 * i];
      sq = fmaf(vals[i], vals[i], sq);
    }
    sq = wred_sum(sq);
    float inv = 1.f / fmaxf(sqrtf(sq), 1e-12f);
#pragma unroll
    for (int i = 0; i < 8; ++i)
      out_sel[((size_t)b * 8 + j) * TOK_ + lane + 64 * i] = vals[i] * inv;
  }
  if (lane == 0) out_numr[b] = (float)numr_s;
}

// ---------------- host launcher -------------------------------------------
extern "C" void kernel_launch(void* const* d_in, const int* in_sizes, int n_in,
                              void* d_out, int out_size, void* d_ws, size_t ws_size,
                              hipStream_t stream) {
  const float* img_feature_proj = (const float*)d_in[0];
  const float* img_patch_feats  = (const float*)d_in[1];
  const float* templates        = (const float*)d_in[2];
  const float* ln1_w  = (const float*)d_in[3];
  const float* ln1_b  = (const float*)d_in[4];
  const float* q_w    = (const float*)d_in[5];
  const float* q_b    = (const float*)d_in[6];
  const float* kv_w   = (const float*)d_in[7];
  const float* kv_b   = (const float*)d_in[8];
  const float* proj_w = (const float*)d_in[9];
  const float* proj_b = (const float*)d_in[10];
  const float* ln2_w  = (const float*)d_in[11];
  const float* ln2_b  = (const float*)d_in[12];
  const float* fc1_w  = (const float*)d_in[13];
  const float* fc1_b  = (const float*)d_in[14];
  const float* fc2_w  = (const float*)d_in[15];
  const float* fc2_b  = (const float*)d_in[16];
  const float* att_fc_w = (const float*)d_in[17];
  const float* att_fc_b = (const float*)d_in[18];

  const size_t XSZ = (size_t)MROWS * D_;          // 20,938,752 floats (84 MB)
  const size_t LATSZ = (size_t)B_ * K_ * TOK_;    // 1,048,576
  const size_t avail = ws_size / sizeof(float);

  // Pick the largest batch-chunk NB whose scratch fits in d_ws.
  int NB = B_;
  while (NB > 1) {
    size_t CH = (size_t)NB * NTOK * D_;
    size_t need = XSZ + 4 * CH + LATSZ + 1024;
    if (need <= avail) break;
    NB >>= 1;
  }
  const size_t CH = (size_t)NB * NTOK * D_;

  float* x      = (float*)d_ws;        // persistent residual stream
  float* hc     = x + XSZ;             // chunk: LN out / attn out
  float* qc     = hc + CH;             // chunk: q
  float* kvc    = qc + CH;             // chunk: kv (2*CH) / fc1 out (2*CH)
  float* lat    = kvc + 2 * CH;
  float* logits = lat + LATSZ;

  // concat
  {
    size_t total = (size_t)MROWS * (D_ / 4);
    concat_kernel<<<(unsigned)((total + 255) / 256), 256, 0, stream>>>(
        templates, img_patch_feats, x);
  }

  const int nchunks = B_ / NB;
  for (int l = 0; l < L_; ++l) {
    for (int c = 0; c < nchunks; ++c) {
      const int b0 = c * NB;
      const int Rc = NB * NTOK;
      const int mt = (Rc + 127) / 128;
      float* xc = x + (size_t)b0 * NTOK * D_;
      ln_kernel<<<Rc, 64, 0, stream>>>(xc, ln1_w + l * D_, ln1_b + l * D_, hc);
      gemm_f32<0, false, false><<<dim3(mt, D_ / 128), 256, 0, stream>>>(
          hc, q_w + (size_t)l * D_ * D_, q_b + l * D_, qc, Rc, D_, D_);
      gemm_f32<0, false, false><<<dim3(mt, 2 * D_ / 128), 256, 0, stream>>>(
          hc, kv_w + (size_t)l * D_ * 2 * D_, kv_b + l * 2 * D_, kvc, Rc, 2 * D_, D_);
      attn_kernel<<<dim3(NB, H_), 256, 0, stream>>>(qc, kvc, hc);
      gemm_f32<0, true, false><<<dim3(mt, D_ / 128), 256, 0, stream>>>(
          hc, proj_w + (size_t)l * D_ * D_, proj_b + l * D_, xc, Rc, D_, D_);
      ln_kernel<<<Rc, 64, 0, stream>>>(xc, ln2_w + l * D_, ln2_b + l * D_, hc);
      gemm_f32<1, false, false><<<dim3(mt, 2 * D_ / 128), 256, 0, stream>>>(
          hc, fc1_w + (size_t)l * D_ * 2 * D_, fc1_b + l * 2 * D_, kvc, Rc, 2 * D_, D_);
      gemm_f32<0, true, false><<<dim3(mt, D_ / 128), 256, 0, stream>>>(
          kvc, fc2_w + (size_t)l * 2 * D_ * D_, fc2_b + l * D_, xc, Rc, D_, 2 * D_);
    }
  }

  // lat = sigmoid(x[:, :16, :] @ att_fc_w + att_fc_b)  (gathered rows)
  gemm_f32<2, false, true><<<dim3((B_ * K_) / 128, TOK_ / 128), 256, 0, stream>>>(
      x, att_fc_w, att_fc_b, lat, B_ * K_, TOK_, D_);

  logits_kernel<<<B_ * K_, 64, 0, stream>>>(lat, img_feature_proj, logits);

  select_kernel<<<B_, 64, 0, stream>>>(logits, lat, (float*)d_out,
                                       (float*)d_out + (size_t)B_ * TOPK_ * TOK_);
}

// Round 5
// 4032.326 us; speedup vs baseline: 3.3592x; 3.3592x over previous
//
#include <hip/hip_runtime.h>
#include <math.h>

// Problem constants
#define B_    128
#define P_    197
#define D_    768
#define TOK_  512
#define K_    16
#define TOPK_ 8
#define L_    2
#define H_    12
#define HD_   64
#define NTOK  213            // K_ + P_
#define MROWS (B_ * NTOK)    // 27264

typedef _Float16 f16;
typedef __attribute__((ext_vector_type(8))) _Float16 f16x8;
typedef __attribute__((ext_vector_type(4))) _Float16 f16x4;
typedef __attribute__((ext_vector_type(4))) float f32x4;

__device__ __forceinline__ float wred_sum(float v) {
#pragma unroll
  for (int o = 32; o > 0; o >>= 1) v += __shfl_xor(v, o);
  return v;
}
__device__ __forceinline__ float wred_max(float v) {
#pragma unroll
  for (int o = 32; o > 0; o >>= 1) v = fmaxf(v, __shfl_xor(v, o));
  return v;
}

// ---------------- concat: x = [templates broadcast | img_patch_feats] ----
__global__ __launch_bounds__(256) void concat_kernel(
    const float* __restrict__ tpl, const float* __restrict__ patches,
    float* __restrict__ x) {
  size_t i = (size_t)blockIdx.x * 256 + threadIdx.x;  // one float4 each
  const size_t total = (size_t)MROWS * (D_ / 4);
  if (i >= total) return;
  size_t row = i / (D_ / 4);
  int c = (int)(i % (D_ / 4)) * 4;
  size_t b = row / NTOK;
  int n = (int)(row % NTOK);
  float4 v;
  if (n < K_) v = *(const float4*)(tpl + (size_t)n * D_ + c);
  else        v = *(const float4*)(patches + ((size_t)b * P_ + (n - K_)) * D_ + c);
  *(float4*)(x + row * D_ + c) = v;
}

// ---------------- LayerNorm: one wave per row, f16 hi/lo split out --------
__global__ __launch_bounds__(64) void ln_split_kernel(
    const float* __restrict__ x, const float* __restrict__ w,
    const float* __restrict__ b, f16* __restrict__ yh, f16* __restrict__ yl) {
  size_t row = blockIdx.x;
  int lane = threadIdx.x;
  const float* xr = x + row * D_;
  float4 v[3];
#pragma unroll
  for (int j = 0; j < 3; ++j) v[j] = *(const float4*)(xr + j * 256 + lane * 4);
  float s = 0.f, sq = 0.f;
#pragma unroll
  for (int j = 0; j < 3; ++j) {
    s += v[j].x + v[j].y + v[j].z + v[j].w;
    sq = fmaf(v[j].x, v[j].x, sq); sq = fmaf(v[j].y, v[j].y, sq);
    sq = fmaf(v[j].z, v[j].z, sq); sq = fmaf(v[j].w, v[j].w, sq);
  }
#pragma unroll
  for (int o = 32; o > 0; o >>= 1) { s += __shfl_xor(s, o); sq += __shfl_xor(sq, o); }
  float mean = s * (1.f / D_);
  float var = sq * (1.f / D_) - mean * mean;
  float rs = rsqrtf(var + 1e-5f);
#pragma unroll
  for (int j = 0; j < 3; ++j) {
    int col = j * 256 + lane * 4;
    float4 wv = *(const float4*)(w + col);
    float4 bv = *(const float4*)(b + col);
    float o0 = (v[j].x - mean) * rs * wv.x + bv.x;
    float o1 = (v[j].y - mean) * rs * wv.y + bv.y;
    float o2 = (v[j].z - mean) * rs * wv.z + bv.z;
    float o3 = (v[j].w - mean) * rs * wv.w + bv.w;
    f16x4 hi = {(f16)o0, (f16)o1, (f16)o2, (f16)o3};
    f16x4 lo = {(f16)(o0 - (float)hi[0]), (f16)(o1 - (float)hi[1]),
                (f16)(o2 - (float)hi[2]), (f16)(o3 - (float)hi[3])};
    *(f16x4*)&yh[row * D_ + col] = hi;
    *(f16x4*)&yl[row * D_ + col] = lo;
  }
}

// -------- weight transpose + f16 hi/lo split: W[K][N] -> Wt[N][K] --------
__global__ __launch_bounds__(256) void transpose_split(
    const float* __restrict__ W, f16* __restrict__ Wh, f16* __restrict__ Wl,
    int Kd, int Nd) {
  __shared__ float t[32][33];
  const int n0 = blockIdx.x * 32, k0 = blockIdx.y * 32;
  const int tx = threadIdx.x & 31, ty = threadIdx.x >> 5;  // 32 x 8
#pragma unroll
  for (int j = 0; j < 4; ++j)
    t[ty + 8 * j][tx] = W[(size_t)(k0 + ty + 8 * j) * Nd + n0 + tx];
  __syncthreads();
#pragma unroll
  for (int j = 0; j < 4; ++j) {
    float v = t[tx][ty + 8 * j];
    f16 hi = (f16)v;
    size_t off = (size_t)(n0 + ty + 8 * j) * Kd + k0 + tx;
    Wh[off] = hi;
    Wl[off] = (f16)(v - (float)hi);
  }
}

// ------- split-f16 MFMA GEMM: C = act(A @ Wt^T + bias) [+C] --------------
// A = Ah+Al (hi/lo f16 planes, [M][K]); Wt = Wh+Wl ([N][K]).
// acc += Ah*Wh + Ah*Wl + Al*Wh  (error ~2^-21 — near-fp32).
// BM=BN=128, BK=32, 256 thr = 4 waves (2x2), wave = 64x64 via 4x4 frags.
// ACT: 0 none, 1 relu, 2 sigmoid. OUTSPLIT: write f16 hi/lo planes.
template <int ACT, bool RESID, bool OUTSPLIT>
__global__ __launch_bounds__(256) void gemm_split(
    const f16* __restrict__ Ah, const f16* __restrict__ Al,
    const f16* __restrict__ Wh, const f16* __restrict__ Wl,
    const float* __restrict__ bias, float* __restrict__ Cf,
    f16* __restrict__ Ch, f16* __restrict__ Cl, int M, int N, int K) {
  __shared__ __align__(16) f16 Ash[128][40];
  __shared__ __align__(16) f16 Asl[128][40];
  __shared__ __align__(16) f16 Bsh[128][40];
  __shared__ __align__(16) f16 Bsl[128][40];
  const int tid = threadIdx.x;
  const int bm = blockIdx.x * 128, bn = blockIdx.y * 128;
  const int w = tid >> 6, lane = tid & 63;
  const int wm = (w & 1) * 64, wn = (w >> 1) * 64;
  const int fr = lane & 15, kg = lane >> 4;
  f32x4 acc[4][4];
  const f32x4 z = {0.f, 0.f, 0.f, 0.f};
#pragma unroll
  for (int i = 0; i < 4; ++i)
#pragma unroll
    for (int j = 0; j < 4; ++j) acc[i][j] = z;
  const int r0 = tid >> 2;            // staging row (0..63), +64 second pass
  const int kc0 = (tid & 3) * 8;      // k-chunk of 8 f16 (16B)
  for (int k0 = 0; k0 < K; k0 += 32) {
#pragma unroll
    for (int i = 0; i < 2; ++i) {
      int r = r0 + i * 64;
      int arow = bm + r; if (arow >= M) arow = M - 1;   // stores guarded
      size_t aoff = (size_t)arow * K + k0 + kc0;
      size_t boff = (size_t)(bn + r) * K + k0 + kc0;
      *(f16x8*)&Ash[r][kc0] = *(const f16x8*)&Ah[aoff];
      *(f16x8*)&Asl[r][kc0] = *(const f16x8*)&Al[aoff];
      *(f16x8*)&Bsh[r][kc0] = *(const f16x8*)&Wh[boff];
      *(f16x8*)&Bsl[r][kc0] = *(const f16x8*)&Wl[boff];
    }
    __syncthreads();
    f16x8 ah[4], al[4], bh[4], bl[4];
#pragma unroll
    for (int i = 0; i < 4; ++i) {
      ah[i] = *(const f16x8*)&Ash[wm + i * 16 + fr][kg * 8];
      al[i] = *(const f16x8*)&Asl[wm + i * 16 + fr][kg * 8];
      bh[i] = *(const f16x8*)&Bsh[wn + i * 16 + fr][kg * 8];
      bl[i] = *(const f16x8*)&Bsl[wn + i * 16 + fr][kg * 8];
    }
#pragma unroll
    for (int i = 0; i < 4; ++i)
#pragma unroll
      for (int j = 0; j < 4; ++j) {
        acc[i][j] = __builtin_amdgcn_mfma_f32_16x16x32_f16(ah[i], bh[j], acc[i][j], 0, 0, 0);
        acc[i][j] = __builtin_amdgcn_mfma_f32_16x16x32_f16(ah[i], bl[j], acc[i][j], 0, 0, 0);
        acc[i][j] = __builtin_amdgcn_mfma_f32_16x16x32_f16(al[i], bh[j], acc[i][j], 0, 0, 0);
      }
    __syncthreads();
  }
  // epilogue: D[row=(lane>>4)*4+rg][col=lane&15] per fragment (m89 layout)
#pragma unroll
  for (int j = 0; j < 4; ++j) {
    const int gc = bn + wn + j * 16 + fr;
    const float bv = bias[gc];
#pragma unroll
    for (int i = 0; i < 4; ++i) {
#pragma unroll
      for (int rg = 0; rg < 4; ++rg) {
        int gr = bm + wm + i * 16 + kg * 4 + rg;
        if (gr < M) {
          float val = acc[i][j][rg] + bv;
          if (ACT == 1) val = fmaxf(val, 0.f);
          if (ACT == 2) val = 1.f / (1.f + expf(-val));
          size_t off = (size_t)gr * N + gc;
          if (OUTSPLIT) {
            f16 hi = (f16)val;
            Ch[off] = hi;
            Cl[off] = (f16)(val - (float)hi);
          } else {
            if (RESID) val += Cf[off];
            Cf[off] = val;
          }
        }
      }
    }
  }
}

// ---------------- flash attention, fp32 in/compute, f16-split out ---------
// Grid (NB, H, 7): 32 q-rows/block, 4 waves x 8 rows. K-tile + transposed
// V-tile in XOR-swizzled [64][64] fp32 LDS. Online softmax.
__global__ __launch_bounds__(256) void attn_kernel2(
    const float* __restrict__ q, const float* __restrict__ kv,
    f16* __restrict__ oh, f16* __restrict__ ol) {
  __shared__ __align__(16) float Kt[64][64];   // Kt[tok][(d4^(tok&15))*4+i]
  __shared__ __align__(16) float Vt[64][64];   // Vt[d][(tg^(d&15))*4+ti]
  __shared__ __align__(16) float qs[4][8][64];
  __shared__ __align__(16) float ps[4][8][64];
  const int b = blockIdx.x, h = blockIdx.y, qt = blockIdx.z;
  const int tid = threadIdx.x, w = tid >> 6, lane = tid & 63;
  const int n0 = qt * 32;
  float o_r[8], m_r[8], l_r[8];
#pragma unroll
  for (int r = 0; r < 8; ++r) { o_r[r] = 0.f; m_r[r] = -INFINITY; l_r[r] = 0.f; }
#pragma unroll
  for (int r = 0; r < 8; ++r) {
    int n = n0 + w * 8 + r;
    if (n >= NTOK) n = NTOK - 1;       // clamp; stores guarded
    qs[w][r][lane] = q[((size_t)(b * NTOK + n)) * D_ + h * HD_ + lane];
  }
  const int swz = lane & 15;
  const f32x4 z4 = {0.f, 0.f, 0.f, 0.f};
  for (int t = 0; t < 4; ++t) {
    const int t0 = t * 64;
    const int TT = (NTOK - t0) < 64 ? (NTOK - t0) : 64;
    __syncthreads();                   // prior tile fully consumed
    for (int s = tid; s < 1024; s += 256) {
      int tok = s >> 4, d4 = s & 15;
      int tkc = tok < TT ? tok : TT - 1;
      size_t base = ((size_t)(b * NTOK + t0 + tkc) * 2) * D_ + h * HD_ + d4 * 4;
      f32x4 kvec = *(const f32x4*)&kv[base];
      *(f32x4*)&Kt[tok][(d4 ^ (tok & 15)) * 4] = kvec;
      f32x4 vvec = *(const f32x4*)&kv[base + D_];
      int tg = tok >> 2, ti = tok & 3;
#pragma unroll
      for (int i = 0; i < 4; ++i) {
        int dd = d4 * 4 + i;
        Vt[dd][((tg ^ (dd & 15)) << 2) | ti] = vvec[i];
      }
    }
    __syncthreads();
    // ---- scores: lane = token ----
    f32x4 sacc[8];
#pragma unroll
    for (int r = 0; r < 8; ++r) sacc[r] = z4;
#pragma unroll 4
    for (int d4 = 0; d4 < 16; ++d4) {
      f32x4 kvv = *(const f32x4*)&Kt[lane][(d4 ^ swz) * 4];
#pragma unroll
      for (int r = 0; r < 8; ++r) {
        f32x4 qv = *(const f32x4*)&qs[w][r][d4 * 4];
        sacc[r] += kvv * qv;
      }
    }
#pragma unroll
    for (int r = 0; r < 8; ++r) {
      float sv = (sacc[r][0] + sacc[r][1]) + (sacc[r][2] + sacc[r][3]);
      sv *= 0.125f;                    // hd^-0.5
      if (lane >= TT) sv = -INFINITY;
      float tmax = wred_max(sv);
      float newm = fmaxf(m_r[r], tmax);
      float e = __expf(sv - newm);     // -inf -> 0
      float tsum = wred_sum(e);
      float scale = __expf(m_r[r] - newm);
      m_r[r] = newm;
      l_r[r] = l_r[r] * scale + tsum;
      o_r[r] *= scale;
      ps[w][r][lane] = e;
    }
    // ---- PV: lane = d ----
    f32x4 pacc[8];
#pragma unroll
    for (int r = 0; r < 8; ++r) pacc[r] = z4;
    const int nm4 = (TT + 3) >> 2;
#pragma unroll 4
    for (int m4 = 0; m4 < nm4; ++m4) {
      f32x4 vv = *(const f32x4*)&Vt[lane][(m4 ^ swz) * 4];
#pragma unroll
      for (int r = 0; r < 8; ++r) {
        f32x4 pv = *(const f32x4*)&ps[w][r][m4 * 4];
        pacc[r] += vv * pv;
      }
    }
#pragma unroll
    for (int r = 0; r < 8; ++r)
      o_r[r] += (pacc[r][0] + pacc[r][1]) + (pacc[r][2] + pacc[r][3]);
  }
#pragma unroll
  for (int r = 0; r < 8; ++r) {
    int n = n0 + w * 8 + r;
    if (n < NTOK) {
      float val = o_r[r] / l_r[r];
      size_t off = ((size_t)(b * NTOK + n)) * D_ + h * HD_ + lane;
      f16 hi = (f16)val;
      oh[off] = hi;
      ol[off] = (f16)(val - (float)hi);
    }
  }
}

// ---------- gather x[:, :16, :] -> f16 hi/lo planes [2048][768] -----------
__global__ __launch_bounds__(256) void gather_split(
    const float* __restrict__ x, f16* __restrict__ oh, f16* __restrict__ ol) {
  int idx = blockIdx.x * 256 + threadIdx.x;
  if (idx >= B_ * K_ * (D_ / 4)) return;
  int row = idx / (D_ / 4);
  int c4 = (idx % (D_ / 4)) * 4;
  int b = row >> 4, k = row & 15;
  const float* src = x + ((size_t)(b * NTOK + k)) * D_ + c4;
  f16x4 hi, lo;
#pragma unroll
  for (int i = 0; i < 4; ++i) {
    float v = src[i];
    hi[i] = (f16)v;
    lo[i] = (f16)(v - (float)hi[i]);
  }
  *(f16x4*)&oh[(size_t)row * D_ + c4] = hi;
  *(f16x4*)&ol[(size_t)row * D_ + c4] = lo;
}

// ---------------- logits[b,k] = dot(lat[b,k,:], proj[b,:]) ----------------
__global__ __launch_bounds__(64) void logits_kernel(
    const float* __restrict__ lat, const float* __restrict__ proj,
    float* __restrict__ logits) {
  int bk = blockIdx.x;
  int b = bk >> 4;
  int lane = threadIdx.x;
  const float* lr = lat + (size_t)bk * TOK_;
  const float* pr = proj + (size_t)b * TOK_;
  float s = 0.f;
#pragma unroll
  for (int i = 0; i < 8; ++i) s = fmaf(lr[lane + 64 * i], pr[lane + 64 * i], s);
  s = wred_sum(s);
  if (lane == 0) logits[bk] = s;
}

// ---------------- softmax + topk select + normalize (1 wave per b) --------
__global__ __launch_bounds__(64) void select_kernel(
    const float* __restrict__ logits, const float* __restrict__ lat,
    float* __restrict__ out_sel, float* __restrict__ out_numr) {
  const int b = blockIdx.x;
  const int lane = threadIdx.x;
  __shared__ float aw_s[16];
  __shared__ int sel_id_s[8];
  __shared__ int numr_s;
  float v = (lane < 16) ? logits[b * 16 + lane] : -INFINITY;
  float mx = wred_max(v);
  float e = (lane < 16) ? expf(v - mx) : 0.f;
  float sum = wred_sum(e);
  float aw = e / sum;
  if (lane < 16) aw_s[lane] = aw;
  unsigned long long ball = __ballot(lane < 16 && aw > 0.05f);
  int counts = __popcll(ball);
  __syncthreads();
  if (lane == 0) {
    int num_r = counts < 1 ? 1 : (counts > TOPK_ ? TOPK_ : counts);
    numr_s = num_r;
    bool used[16];
#pragma unroll
    for (int i = 0; i < 16; ++i) used[i] = false;
    int sorted_idx[8];
    for (int j = 0; j < 8; ++j) {   // descending top-8 (ties: lowest index)
      float bv = -INFINITY; int bi = 0;
      for (int i = 0; i < 16; ++i)
        if (!used[i] && aw_s[i] > bv) { bv = aw_s[i]; bi = i; }
      used[bi] = true;
      sorted_idx[j] = bi;
    }
    int keys[8];
    for (int j = 0; j < 8; ++j) keys[j] = (j < num_r) ? sorted_idx[j] : (16 + j);
    bool kused[8];
    for (int j = 0; j < 8; ++j) kused[j] = false;
    for (int slot = 0; slot < 8; ++slot) {  // perm = argsort(keys), gather
      int bk = 1 << 30, bj = 0;
      for (int j = 0; j < 8; ++j)
        if (!kused[j] && keys[j] < bk) { bk = keys[j]; bj = j; }
      kused[bj] = true;
      sel_id_s[slot] = sorted_idx[bj];
    }
  }
  __syncthreads();
  for (int j = 0; j < 8; ++j) {
    int id = sel_id_s[j];
    const float* row = lat + ((size_t)b * 16 + id) * TOK_;
    float vals[8];
    float sq = 0.f;
#pragma unroll
    for (int i = 0; i < 8; ++i) {
      vals[i] = row[lane + 64 * i];
      sq = fmaf(vals[i], vals[i], sq);
    }
    sq = wred_sum(sq);
    float inv = 1.f / fmaxf(sqrtf(sq), 1e-12f);
#pragma unroll
    for (int i = 0; i < 8; ++i)
      out_sel[((size_t)b * 8 + j) * TOK_ + lane + 64 * i] = vals[i] * inv;
  }
  if (lane == 0) out_numr[b] = (float)numr_s;
}

// ---------------- host launcher -------------------------------------------
extern "C" void kernel_launch(void* const* d_in, const int* in_sizes, int n_in,
                              void* d_out, int out_size, void* d_ws, size_t ws_size,
                              hipStream_t stream) {
  const float* img_feature_proj = (const float*)d_in[0];
  const float* img_patch_feats  = (const float*)d_in[1];
  const float* templates        = (const float*)d_in[2];
  const float* ln1_w  = (const float*)d_in[3];
  const float* ln1_b  = (const float*)d_in[4];
  const float* q_w    = (const float*)d_in[5];
  const float* q_b    = (const float*)d_in[6];
  const float* kv_w   = (const float*)d_in[7];
  const float* kv_b   = (const float*)d_in[8];
  const float* proj_w = (const float*)d_in[9];
  const float* proj_b = (const float*)d_in[10];
  const float* ln2_w  = (const float*)d_in[11];
  const float* ln2_b  = (const float*)d_in[12];
  const float* fc1_w  = (const float*)d_in[13];
  const float* fc1_b  = (const float*)d_in[14];
  const float* fc2_w  = (const float*)d_in[15];
  const float* fc2_b  = (const float*)d_in[16];
  const float* att_fc_w = (const float*)d_in[17];
  const float* att_fc_b = (const float*)d_in[18];

  // ---- fixed workspace (~115 MB) ----
  char* ws = (char*)d_ws;
  const size_t XB = (size_t)MROWS * D_ * 4;              // 83,755,008 B
  float* x_f = (float*)ws;  ws += XB;                    // residual fp32
  auto alloc_f16 = [&](size_t n) { f16* p = (f16*)ws; ws += n * 2; return p; };
  f16* wq_h  = alloc_f16((size_t)768 * 768);
  f16* wq_l  = alloc_f16((size_t)768 * 768);
  f16* wkv_h = alloc_f16((size_t)1536 * 768);
  f16* wkv_l = alloc_f16((size_t)1536 * 768);
  f16* wp_h  = alloc_f16((size_t)768 * 768);
  f16* wp_l  = alloc_f16((size_t)768 * 768);
  f16* wf1_h = alloc_f16((size_t)1536 * 768);
  f16* wf1_l = alloc_f16((size_t)1536 * 768);
  f16* wf2_h = alloc_f16((size_t)768 * 1536);
  f16* wf2_l = alloc_f16((size_t)768 * 1536);
  f16* awt_h = alloc_f16((size_t)512 * 768);
  f16* awt_l = alloc_f16((size_t)512 * 768);
  f16* lat_h = alloc_f16((size_t)2048 * 768);
  f16* lat_l = alloc_f16((size_t)2048 * 768);
  float* lat    = (float*)ws; ws += (size_t)2048 * 512 * 4;
  float* logits = (float*)ws; ws += 8192;
  const size_t fixed_bytes = (size_t)(ws - (char*)d_ws);

  // ---- adaptive batch-chunk: h planes(4B) + q_f(4B) + kv_f(8B) per elem
  int NB = B_;
  while (NB > 1) {
    size_t CHE = (size_t)NB * NTOK * D_;
    if (fixed_bytes + 16 * CHE <= ws_size) break;
    NB >>= 1;
  }
  const size_t CHE = (size_t)NB * NTOK * D_;
  f16* h_h = (f16*)ws;                         // CHE f16
  f16* h_l = h_h + CHE;                        // CHE f16
  float* q_f  = (float*)(h_l + CHE);           // CHE f32
  float* kv_f = q_f + CHE;                     // 2*CHE f32
  f16* fc1o_h = (f16*)q_f;                     // alias: 2*CHE f16
  f16* fc1o_l = (f16*)kv_f;                    // alias: 2*CHE f16

  // ---- concat ----
  {
    size_t total = (size_t)MROWS * (D_ / 4);
    concat_kernel<<<(unsigned)((total + 255) / 256), 256, 0, stream>>>(
        templates, img_patch_feats, x_f);
  }
  transpose_split<<<dim3(16, 24), 256, 0, stream>>>(att_fc_w, awt_h, awt_l, 768, 512);

  const int nchunks = B_ / NB;
  for (int l = 0; l < L_; ++l) {
    transpose_split<<<dim3(24, 24), 256, 0, stream>>>(q_w + (size_t)l * 768 * 768, wq_h, wq_l, 768, 768);
    transpose_split<<<dim3(48, 24), 256, 0, stream>>>(kv_w + (size_t)l * 768 * 1536, wkv_h, wkv_l, 768, 1536);
    transpose_split<<<dim3(24, 24), 256, 0, stream>>>(proj_w + (size_t)l * 768 * 768, wp_h, wp_l, 768, 768);
    transpose_split<<<dim3(48, 24), 256, 0, stream>>>(fc1_w + (size_t)l * 768 * 1536, wf1_h, wf1_l, 768, 1536);
    transpose_split<<<dim3(24, 48), 256, 0, stream>>>(fc2_w + (size_t)l * 1536 * 768, wf2_h, wf2_l, 1536, 768);
    for (int c = 0; c < nchunks; ++c) {
      const int b0 = c * NB;
      const int Rc = NB * NTOK;
      const int mt = (Rc + 127) / 128;
      float* xc = x_f + (size_t)b0 * NTOK * D_;
      ln_split_kernel<<<Rc, 64, 0, stream>>>(xc, ln1_w + l * D_, ln1_b + l * D_, h_h, h_l);
      gemm_split<0, false, false><<<dim3(mt, 6), 256, 0, stream>>>(
          h_h, h_l, wq_h, wq_l, q_b + l * D_, q_f, nullptr, nullptr, Rc, 768, 768);
      gemm_split<0, false, false><<<dim3(mt, 12), 256, 0, stream>>>(
          h_h, h_l, wkv_h, wkv_l, kv_b + l * 1536, kv_f, nullptr, nullptr, Rc, 1536, 768);
      attn_kernel2<<<dim3(NB, H_, 7), 256, 0, stream>>>(q_f, kv_f, h_h, h_l);
      gemm_split<0, true, false><<<dim3(mt, 6), 256, 0, stream>>>(
          h_h, h_l, wp_h, wp_l, proj_b + l * D_, xc, nullptr, nullptr, Rc, 768, 768);
      ln_split_kernel<<<Rc, 64, 0, stream>>>(xc, ln2_w + l * D_, ln2_b + l * D_, h_h, h_l);
      gemm_split<1, false, true><<<dim3(mt, 12), 256, 0, stream>>>(
          h_h, h_l, wf1_h, wf1_l, fc1_b + l * 1536, nullptr, fc1o_h, fc1o_l, Rc, 1536, 768);
      gemm_split<0, true, false><<<dim3(mt, 6), 256, 0, stream>>>(
          fc1o_h, fc1o_l, wf2_h, wf2_l, fc2_b + l * D_, xc, nullptr, nullptr, Rc, 768, 1536);
    }
  }

  gather_split<<<(B_ * K_ * (D_ / 4) + 255) / 256, 256, 0, stream>>>(x_f, lat_h, lat_l);
  gemm_split<2, false, false><<<dim3(16, 4), 256, 0, stream>>>(
      lat_h, lat_l, awt_h, awt_l, att_fc_b, lat, nullptr, nullptr, B_ * K_, TOK_, 768);

  logits_kernel<<<B_ * K_, 64, 0, stream>>>(lat, img_feature_proj, logits);
  select_kernel<<<B_, 64, 0, stream>>>(logits, lat, (float*)d_out,
                                       (float*)d_out + (size_t)B_ * TOPK_ * TOK_);
}